// Round 9
// baseline (545.643 us; speedup 1.0000x reference)
//
#include <hip/hip_runtime.h>

typedef unsigned short u16;
typedef __attribute__((ext_vector_type(8))) short bf16x8;  // 8 bf16 (4 VGPRs)
typedef __attribute__((ext_vector_type(4))) float f32x4;   // MFMA C/D frag

__device__ __forceinline__ float bf2f(u16 x) {
  union { unsigned u; float f; } v; v.u = ((unsigned)x) << 16; return v.f;
}
__device__ __forceinline__ u16 f2bf(float f) {
  union { float f; unsigned u; } v; v.f = f;
  unsigned r = v.u + 0x7FFFu + ((v.u >> 16) & 1u);  // RNE
  return (u16)(r >> 16);
}
__device__ __forceinline__ float clampf(float v) {
  return fmaxf(fminf(v, 1.0e4f), -1.0e4f);
}

// ---------- convert x (f32) -> bf16 ----------
__global__ __launch_bounds__(256) void convert_x(
    const float* __restrict__ x, u16* __restrict__ xbf) {
  const int i0 = (blockIdx.x * 256 + threadIdx.x) * 4;
  const float4 v = *(const float4*)(x + i0);
  xbf[i0 + 0] = f2bf(v.x); xbf[i0 + 1] = f2bf(v.y);
  xbf[i0 + 2] = f2bf(v.z); xbf[i0 + 3] = f2bf(v.w);
}

// ---------- transpose f32 in[R][C] -> bf16 out[C][R] ----------
__global__ __launch_bounds__(256) void transpose_f32_bf16(
    const float* __restrict__ in, u16* __restrict__ out, int R, int C) {
  __shared__ u16 tile[32][33];
  const int bc = blockIdx.x * 32, br = blockIdx.y * 32;
  const int tx = threadIdx.x & 31, ty = threadIdx.x >> 5;
  #pragma unroll
  for (int i = ty; i < 32; i += 8)
    tile[i][tx] = f2bf(in[(size_t)(br + i) * C + bc + tx]);
  __syncthreads();
  #pragma unroll
  for (int i = ty; i < 32; i += 8)
    out[(size_t)(bc + i) * R + br + tx] = tile[tx][i];
}

// ---------- GEMM1: QKV projection, dual-output epilogue (unchanged) ----------
#define LDT 40  // 32 + 8 pad; 80B rows keep 16B alignment

__global__ __launch_bounds__(256) void gemm1_qkv(
    const u16* __restrict__ A, const u16* __restrict__ Bt,
    const float* __restrict__ bias, u16* __restrict__ qk,
    u16* __restrict__ vt, int K) {
  __shared__ u16 As[128 * LDT];
  __shared__ u16 Bs[128 * LDT];
  const int tid = threadIdx.x;
  const int m0 = blockIdx.y * 128, n0 = blockIdx.x * 128;
  const int wave = tid >> 6, lane = tid & 63;
  const int quad = lane >> 4, l16 = lane & 15;
  const int wm = (wave >> 1) * 64, wn = (wave & 1) * 64;
  const int sr = tid >> 2, sp = tid & 3;

  f32x4 acc[4][4] = {};
  const u16* gA = A + (size_t)(m0 + sr) * K + sp * 8;
  const u16* gB = Bt + (size_t)(n0 + sr) * K + sp * 8;

  for (int k0 = 0; k0 < K; k0 += 32) {
    *(bf16x8*)&As[sr * LDT + sp * 8]        = *(const bf16x8*)(gA + k0);
    *(bf16x8*)&As[(sr + 64) * LDT + sp * 8] = *(const bf16x8*)(gA + (size_t)64 * K + k0);
    *(bf16x8*)&Bs[sr * LDT + sp * 8]        = *(const bf16x8*)(gB + k0);
    *(bf16x8*)&Bs[(sr + 64) * LDT + sp * 8] = *(const bf16x8*)(gB + (size_t)64 * K + k0);
    __syncthreads();
    bf16x8 af[4], bfr[4];
    #pragma unroll
    for (int i = 0; i < 4; ++i)
      af[i] = *(const bf16x8*)&As[(wm + i * 16 + l16) * LDT + quad * 8];
    #pragma unroll
    for (int j = 0; j < 4; ++j)
      bfr[j] = *(const bf16x8*)&Bs[(wn + j * 16 + l16) * LDT + quad * 8];
    #pragma unroll
    for (int i = 0; i < 4; ++i)
      #pragma unroll
      for (int j = 0; j < 4; ++j)
        acc[i][j] = __builtin_amdgcn_mfma_f32_16x16x32_bf16(af[i], bfr[j], acc[i][j], 0, 0, 0);
    __syncthreads();
  }

  #pragma unroll
  for (int i = 0; i < 4; ++i) {
    const int row = m0 + wm + i * 16 + quad * 4;
    #pragma unroll
    for (int j = 0; j < 4; ++j) {
      const int col = n0 + wn + j * 16 + l16;
      const float bv = bias[col];
      if (col < 2048) {
        #pragma unroll
        for (int r = 0; r < 4; ++r)
          qk[(size_t)(row + r) * 2048 + col] = f2bf(clampf(acc[i][j][r] + bv));
      } else {
        const int d = col & 63;
        const int hh = (col - 2048) >> 6;
        #pragma unroll
        for (int r = 0; r < 4; ++r) {
          const int rr = row + r;
          const int bb = rr >> 11, ss = rr & 2047;
          vt[(size_t)(bb * 16 + hh) * 131072 + d * 2048 + ss] =
              f2bf(clampf(acc[i][j][r] + bv));
        }
      }
    }
  }
}

// ---------- GEMM2: out(f32) = ctx * w_proj^T + bias (unchanged) ----------
__global__ __launch_bounds__(256) void gemm2_proj(
    const u16* __restrict__ A, const u16* __restrict__ Bt,
    const float* __restrict__ bias, float* __restrict__ out, int K) {
  __shared__ u16 As[128 * LDT];
  __shared__ u16 Bs[128 * LDT];
  const int tid = threadIdx.x;
  const int m0 = blockIdx.y * 128, n0 = blockIdx.x * 128;
  const int wave = tid >> 6, lane = tid & 63;
  const int quad = lane >> 4, l16 = lane & 15;
  const int wm = (wave >> 1) * 64, wn = (wave & 1) * 64;
  const int sr = tid >> 2, sp = tid & 3;

  f32x4 acc[4][4] = {};
  const u16* gA = A + (size_t)(m0 + sr) * K + sp * 8;
  const u16* gB = Bt + (size_t)(n0 + sr) * K + sp * 8;

  for (int k0 = 0; k0 < K; k0 += 32) {
    *(bf16x8*)&As[sr * LDT + sp * 8]        = *(const bf16x8*)(gA + k0);
    *(bf16x8*)&As[(sr + 64) * LDT + sp * 8] = *(const bf16x8*)(gA + (size_t)64 * K + k0);
    *(bf16x8*)&Bs[sr * LDT + sp * 8]        = *(const bf16x8*)(gB + k0);
    *(bf16x8*)&Bs[(sr + 64) * LDT + sp * 8] = *(const bf16x8*)(gB + (size_t)64 * K + k0);
    __syncthreads();
    bf16x8 af[4], bfr[4];
    #pragma unroll
    for (int i = 0; i < 4; ++i)
      af[i] = *(const bf16x8*)&As[(wm + i * 16 + l16) * LDT + quad * 8];
    #pragma unroll
    for (int j = 0; j < 4; ++j)
      bfr[j] = *(const bf16x8*)&Bs[(wn + j * 16 + l16) * LDT + quad * 8];
    #pragma unroll
    for (int i = 0; i < 4; ++i)
      #pragma unroll
      for (int j = 0; j < 4; ++j)
        acc[i][j] = __builtin_amdgcn_mfma_f32_16x16x32_bf16(af[i], bfr[j], acc[i][j], 0, 0, 0);
    __syncthreads();
  }

  #pragma unroll
  for (int i = 0; i < 4; ++i) {
    const int row = m0 + wm + i * 16 + quad * 4;
    #pragma unroll
    for (int j = 0; j < 4; ++j) {
      const int col = n0 + wn + j * 16 + l16;
      const float bv = bias[col];
      #pragma unroll
      for (int r = 0; r < 4; ++r)
        out[(size_t)(row + r) * 1024 + col] = clampf(acc[i][j][r] + bv);
    }
  }
}

// ---------- fused flash attention, v3 ----------
// 1 wave/block, grid (bh=64, qt=64), wave owns 32 q-rows, no barriers.
// v3: K-tile register prefetch (distance 1, ping-pong via unroll-2) hides the
// load->QK chain head; softmax consumed per-jj so score regs stay at 8 (keeps
// VGPR+AGPR <= 128 so launch_bounds(64,4) holds 4 waves/SIMD).
__global__ __launch_bounds__(64, 4) void attn_fused(
    const u16* __restrict__ qk, const u16* __restrict__ vt,
    u16* __restrict__ ctx) {
  __shared__ u16 Pl[32][72];  // P[32 q][64 kv], pad->72
  const int bh = blockIdx.x, qt = blockIdx.y;
  const int b = bh >> 4, h = bh & 15;
  const int lane = threadIdx.x;
  const int quad = lane >> 4, l16 = lane & 15;
  const int qbase = qt * 32;

  const u16* qptr = qk + (size_t)(b * 2048) * 2048 + h * 64;
  bf16x8 qf[2][2];
  #pragma unroll
  for (int i = 0; i < 2; ++i)
    #pragma unroll
    for (int ks = 0; ks < 2; ++ks)
      qf[i][ks] = *(const bf16x8*)(qptr + (size_t)(qbase + i * 16 + l16) * 2048 + ks * 32 + quad * 8);

  const u16* kptr = qk + (size_t)(b * 2048) * 2048 + 1024 + h * 64;
  const u16* vptr = vt + (size_t)bh * 131072;

  f32x4 o[2][4] = {};
  f32x4 lsum[2] = {};
  const float c2 = 0.125f * 1.44269504088896340736f;  // SCALE * log2(e)

  // prefetch K tile for kv0 = 0
  bf16x8 kf[8];
  #pragma unroll
  for (int jj = 0; jj < 4; ++jj)
    #pragma unroll
    for (int ks = 0; ks < 2; ++ks)
      kf[jj * 2 + ks] = *(const bf16x8*)(kptr + (size_t)(jj * 16 + l16) * 2048 + ks * 32 + quad * 8);

  #pragma unroll 2
  for (int kv0 = 0; kv0 < 2048; kv0 += 64) {
    // issue next K tile (wraps to 0 on last iter; loads valid, discarded)
    const int kvn = (kv0 + 64) & 2047;
    bf16x8 kn[8];
    #pragma unroll
    for (int jj = 0; jj < 4; ++jj)
      #pragma unroll
      for (int ks = 0; ks < 2; ++ks)
        kn[jj * 2 + ks] = *(const bf16x8*)(kptr + (size_t)(kvn + jj * 16 + l16) * 2048 + ks * 32 + quad * 8);

    // QK^T + softmax, one 16-kv column at a time (s live = 8 regs)
    #pragma unroll
    for (int jj = 0; jj < 4; ++jj) {
      f32x4 s0 = {}, s1 = {};
      #pragma unroll
      for (int ks = 0; ks < 2; ++ks) {
        s0 = __builtin_amdgcn_mfma_f32_16x16x32_bf16(qf[0][ks], kf[jj * 2 + ks], s0, 0, 0, 0);
        s1 = __builtin_amdgcn_mfma_f32_16x16x32_bf16(qf[1][ks], kf[jj * 2 + ks], s1, 0, 0, 0);
      }
      #pragma unroll
      for (int r = 0; r < 4; ++r) {
        const float p0 = exp2f(s0[r] * c2);
        lsum[0][r] += p0;
        union { float f; unsigned u; } v0; v0.f = p0;
        Pl[quad * 4 + r][jj * 16 + l16] = (u16)((v0.u + 0x8000u) >> 16);
        const float p1 = exp2f(s1[r] * c2);
        lsum[1][r] += p1;
        union { float f; unsigned u; } v1; v1.f = p1;
        Pl[16 + quad * 4 + r][jj * 16 + l16] = (u16)((v1.u + 0x8000u) >> 16);
      }
    }
    // PV: o += P(32x64) . V^T(64x64)   (V loads interleaved; covered by kn in flight)
    #pragma unroll
    for (int ks = 0; ks < 2; ++ks) {
      bf16x8 af0 = *(const bf16x8*)&Pl[l16][ks * 32 + quad * 8];
      bf16x8 af1 = *(const bf16x8*)&Pl[16 + l16][ks * 32 + quad * 8];
      #pragma unroll
      for (int j = 0; j < 4; ++j) {
        bf16x8 vf = *(const bf16x8*)(vptr + (size_t)(j * 16 + l16) * 2048 + kv0 + ks * 32 + quad * 8);
        o[0][j] = __builtin_amdgcn_mfma_f32_16x16x32_bf16(af0, vf, o[0][j], 0, 0, 0);
        o[1][j] = __builtin_amdgcn_mfma_f32_16x16x32_bf16(af1, vf, o[1][j], 0, 0, 0);
      }
    }
    // rotate prefetch buffer (unroll-2 lets the allocator elide the moves)
    #pragma unroll
    for (int t = 0; t < 8; ++t) kf[t] = kn[t];
  }

  // epilogue: reduce l over the 16 lanes of each quad, normalize, write ctx
  #pragma unroll
  for (int i = 0; i < 2; ++i)
    #pragma unroll
    for (int r = 0; r < 4; ++r) {
      float lv = lsum[i][r];
      #pragma unroll
      for (int d = 1; d < 16; d <<= 1) lv += __shfl_xor(lv, d, 64);
      lsum[i][r] = lv;
    }
  u16* cbase = ctx + (size_t)(b * 2048) * 1024 + h * 64;
  #pragma unroll
  for (int i = 0; i < 2; ++i)
    #pragma unroll
    for (int r = 0; r < 4; ++r) {
      const float inv = 1.0f / lsum[i][r];
      const int q = qbase + i * 16 + quad * 4 + r;
      #pragma unroll
      for (int j = 0; j < 4; ++j)
        cbase[(size_t)q * 1024 + j * 16 + l16] = f2bf(o[i][j][r] * inv);
    }
}

extern "C" void kernel_launch(void* const* d_in, const int* in_sizes, int n_in,
                              void* d_out, int out_size, void* d_ws, size_t ws_size,
                              hipStream_t stream) {
  (void)out_size;
  const float *x = nullptr, *wq = nullptr, *bq = nullptr, *wp = nullptr, *bp = nullptr;
  for (int i = 0; i < n_in; ++i) {
    switch (in_sizes[i]) {
      case 8388608: x  = (const float*)d_in[i]; break;
      case 3145728: wq = (const float*)d_in[i]; break;
      case 3072:    bq = (const float*)d_in[i]; break;
      case 1048576: wp = (const float*)d_in[i]; break;
      case 1024:    bp = (const float*)d_in[i]; break;
      default: break;
    }
  }
  if (!x || !wq || !bq || !wp || !bp) {
    x  = (const float*)d_in[0]; wq = (const float*)d_in[1];
    bq = (const float*)d_in[2]; wp = (const float*)d_in[3];
    bp = (const float*)d_in[4];
  }
  float* out = (float*)d_out;  // f32 output (established R7)

  const size_t NEED = 75497472;
  if (ws_size < NEED) return;

  char* ws = (char*)d_ws;
  u16* qkb = (u16*)(ws);              // [8192][2048] Q,K
  u16* vt  = (u16*)(ws + 33554432);   // [64][64][2048] V^T
  u16* xbf = (u16*)(ws + 50331648);   // x_bf, then ctx
  u16* wT1 = (u16*)(ws + 67108864);
  u16* wT2 = (u16*)(ws + 73400320);

  convert_x<<<8192, 256, 0, stream>>>(x, xbf);
  transpose_f32_bf16<<<dim3(96, 32), 256, 0, stream>>>(wq, wT1, 1024, 3072);
  transpose_f32_bf16<<<dim3(32, 32), 256, 0, stream>>>(wp, wT2, 1024, 1024);
  gemm1_qkv<<<dim3(24, 64), 256, 0, stream>>>(xbf, wT1, bq, qkb, vt, 1024);
  attn_fused<<<dim3(64, 64), 64, 0, stream>>>(qkb, vt, xbf /*ctx*/);
  gemm2_proj<<<dim3(8, 64), 256, 0, stream>>>(xbf /*ctx*/, wT2, bp, out, 1024);
}

// Round 10
// 448.736 us; speedup vs baseline: 1.2160x; 1.2160x over previous
//
#include <hip/hip_runtime.h>

typedef unsigned short u16;
typedef __attribute__((ext_vector_type(8))) short bf16x8;  // 8 bf16 (4 VGPRs)
typedef __attribute__((ext_vector_type(4))) float f32x4;   // MFMA C/D frag

__device__ __forceinline__ float bf2f(u16 x) {
  union { unsigned u; float f; } v; v.u = ((unsigned)x) << 16; return v.f;
}
__device__ __forceinline__ u16 f2bf(float f) {
  union { float f; unsigned u; } v; v.f = f;
  unsigned r = v.u + 0x7FFFu + ((v.u >> 16) & 1u);  // RNE
  return (u16)(r >> 16);
}
__device__ __forceinline__ float clampf(float v) {
  return fmaxf(fminf(v, 1.0e4f), -1.0e4f);
}

// ---------- convert x (f32) -> bf16 ----------
__global__ __launch_bounds__(256) void convert_x(
    const float* __restrict__ x, u16* __restrict__ xbf) {
  const int i0 = (blockIdx.x * 256 + threadIdx.x) * 4;
  const float4 v = *(const float4*)(x + i0);
  xbf[i0 + 0] = f2bf(v.x); xbf[i0 + 1] = f2bf(v.y);
  xbf[i0 + 2] = f2bf(v.z); xbf[i0 + 3] = f2bf(v.w);
}

// ---------- transpose f32 in[R][C] -> bf16 out[C][R] ----------
__global__ __launch_bounds__(256) void transpose_f32_bf16(
    const float* __restrict__ in, u16* __restrict__ out, int R, int C) {
  __shared__ u16 tile[32][33];
  const int bc = blockIdx.x * 32, br = blockIdx.y * 32;
  const int tx = threadIdx.x & 31, ty = threadIdx.x >> 5;
  #pragma unroll
  for (int i = ty; i < 32; i += 8)
    tile[i][tx] = f2bf(in[(size_t)(br + i) * C + bc + tx]);
  __syncthreads();
  #pragma unroll
  for (int i = ty; i < 32; i += 8)
    out[(size_t)(bc + i) * R + br + tx] = tile[tx][i];
}

// ---------- GEMM1: QKV projection, dual-output epilogue (unchanged) ----------
#define LDT 40  // 32 + 8 pad; 80B rows keep 16B alignment

__global__ __launch_bounds__(256) void gemm1_qkv(
    const u16* __restrict__ A, const u16* __restrict__ Bt,
    const float* __restrict__ bias, u16* __restrict__ qk,
    u16* __restrict__ vt, int K) {
  __shared__ u16 As[128 * LDT];
  __shared__ u16 Bs[128 * LDT];
  const int tid = threadIdx.x;
  const int m0 = blockIdx.y * 128, n0 = blockIdx.x * 128;
  const int wave = tid >> 6, lane = tid & 63;
  const int quad = lane >> 4, l16 = lane & 15;
  const int wm = (wave >> 1) * 64, wn = (wave & 1) * 64;
  const int sr = tid >> 2, sp = tid & 3;

  f32x4 acc[4][4] = {};
  const u16* gA = A + (size_t)(m0 + sr) * K + sp * 8;
  const u16* gB = Bt + (size_t)(n0 + sr) * K + sp * 8;

  for (int k0 = 0; k0 < K; k0 += 32) {
    *(bf16x8*)&As[sr * LDT + sp * 8]        = *(const bf16x8*)(gA + k0);
    *(bf16x8*)&As[(sr + 64) * LDT + sp * 8] = *(const bf16x8*)(gA + (size_t)64 * K + k0);
    *(bf16x8*)&Bs[sr * LDT + sp * 8]        = *(const bf16x8*)(gB + k0);
    *(bf16x8*)&Bs[(sr + 64) * LDT + sp * 8] = *(const bf16x8*)(gB + (size_t)64 * K + k0);
    __syncthreads();
    bf16x8 af[4], bfr[4];
    #pragma unroll
    for (int i = 0; i < 4; ++i)
      af[i] = *(const bf16x8*)&As[(wm + i * 16 + l16) * LDT + quad * 8];
    #pragma unroll
    for (int j = 0; j < 4; ++j)
      bfr[j] = *(const bf16x8*)&Bs[(wn + j * 16 + l16) * LDT + quad * 8];
    #pragma unroll
    for (int i = 0; i < 4; ++i)
      #pragma unroll
      for (int j = 0; j < 4; ++j)
        acc[i][j] = __builtin_amdgcn_mfma_f32_16x16x32_bf16(af[i], bfr[j], acc[i][j], 0, 0, 0);
    __syncthreads();
  }

  #pragma unroll
  for (int i = 0; i < 4; ++i) {
    const int row = m0 + wm + i * 16 + quad * 4;
    #pragma unroll
    for (int j = 0; j < 4; ++j) {
      const int col = n0 + wn + j * 16 + l16;
      const float bv = bias[col];
      if (col < 2048) {
        #pragma unroll
        for (int r = 0; r < 4; ++r)
          qk[(size_t)(row + r) * 2048 + col] = f2bf(clampf(acc[i][j][r] + bv));
      } else {
        const int d = col & 63;
        const int hh = (col - 2048) >> 6;
        #pragma unroll
        for (int r = 0; r < 4; ++r) {
          const int rr = row + r;
          const int bb = rr >> 11, ss = rr & 2047;
          vt[(size_t)(bb * 16 + hh) * 131072 + d * 2048 + ss] =
              f2bf(clampf(acc[i][j][r] + bv));
        }
      }
    }
  }
}

// ---------- GEMM2: out(f32) = ctx * w_proj^T + bias (unchanged) ----------
__global__ __launch_bounds__(256) void gemm2_proj(
    const u16* __restrict__ A, const u16* __restrict__ Bt,
    const float* __restrict__ bias, float* __restrict__ out, int K) {
  __shared__ u16 As[128 * LDT];
  __shared__ u16 Bs[128 * LDT];
  const int tid = threadIdx.x;
  const int m0 = blockIdx.y * 128, n0 = blockIdx.x * 128;
  const int wave = tid >> 6, lane = tid & 63;
  const int quad = lane >> 4, l16 = lane & 15;
  const int wm = (wave >> 1) * 64, wn = (wave & 1) * 64;
  const int sr = tid >> 2, sp = tid & 3;

  f32x4 acc[4][4] = {};
  const u16* gA = A + (size_t)(m0 + sr) * K + sp * 8;
  const u16* gB = Bt + (size_t)(n0 + sr) * K + sp * 8;

  for (int k0 = 0; k0 < K; k0 += 32) {
    *(bf16x8*)&As[sr * LDT + sp * 8]        = *(const bf16x8*)(gA + k0);
    *(bf16x8*)&As[(sr + 64) * LDT + sp * 8] = *(const bf16x8*)(gA + (size_t)64 * K + k0);
    *(bf16x8*)&Bs[sr * LDT + sp * 8]        = *(const bf16x8*)(gB + k0);
    *(bf16x8*)&Bs[(sr + 64) * LDT + sp * 8] = *(const bf16x8*)(gB + (size_t)64 * K + k0);
    __syncthreads();
    bf16x8 af[4], bfr[4];
    #pragma unroll
    for (int i = 0; i < 4; ++i)
      af[i] = *(const bf16x8*)&As[(wm + i * 16 + l16) * LDT + quad * 8];
    #pragma unroll
    for (int j = 0; j < 4; ++j)
      bfr[j] = *(const bf16x8*)&Bs[(wn + j * 16 + l16) * LDT + quad * 8];
    #pragma unroll
    for (int i = 0; i < 4; ++i)
      #pragma unroll
      for (int j = 0; j < 4; ++j)
        acc[i][j] = __builtin_amdgcn_mfma_f32_16x16x32_bf16(af[i], bfr[j], acc[i][j], 0, 0, 0);
    __syncthreads();
  }

  #pragma unroll
  for (int i = 0; i < 4; ++i) {
    const int row = m0 + wm + i * 16 + quad * 4;
    #pragma unroll
    for (int j = 0; j < 4; ++j) {
      const int col = n0 + wn + j * 16 + l16;
      const float bv = bias[col];
      #pragma unroll
      for (int r = 0; r < 4; ++r)
        out[(size_t)(row + r) * 1024 + col] = clampf(acc[i][j][r] + bv);
    }
  }
}

// ---------- fused flash attention, v4 ----------
// R8 structure (1 wave/block, grid (64,64), no barriers, transient per-jj K
// loads) + ONE change: the 8 V-tile loads are hoisted before the softmax so
// their ~600cyc latency is covered by the softmax VALU block instead of
// serializing after the Pl LDS turnaround. No cross-iteration register
// buffers, no rotation (R9's kf/kn ping-pong spilled to scratch: WRITE_SIZE
// 16->534 MB, 252->361 us). Peak live ~116 regs <= 128 cap of (64,4).
__global__ __launch_bounds__(64, 4) void attn_fused(
    const u16* __restrict__ qk, const u16* __restrict__ vt,
    u16* __restrict__ ctx) {
  __shared__ u16 Pl[32][72];  // P[32 q][64 kv], pad->72
  const int bh = blockIdx.x, qt = blockIdx.y;
  const int b = bh >> 4, h = bh & 15;
  const int lane = threadIdx.x;
  const int quad = lane >> 4, l16 = lane & 15;
  const int qbase = qt * 32;

  const u16* qptr = qk + (size_t)(b * 2048) * 2048 + h * 64;
  bf16x8 qf[2][2];
  #pragma unroll
  for (int i = 0; i < 2; ++i)
    #pragma unroll
    for (int ks = 0; ks < 2; ++ks)
      qf[i][ks] = *(const bf16x8*)(qptr + (size_t)(qbase + i * 16 + l16) * 2048 + ks * 32 + quad * 8);

  const u16* kptr = qk + (size_t)(b * 2048) * 2048 + 1024 + h * 64;
  const u16* vptr = vt + (size_t)bh * 131072;

  f32x4 o[2][4] = {};
  f32x4 lsum[2] = {};
  const float c2 = 0.125f * 1.44269504088896340736f;  // SCALE * log2(e)

  for (int kv0 = 0; kv0 < 2048; kv0 += 64) {
    // QK^T for a 32q x 64kv tile (K frags loaded transiently per column)
    f32x4 s[2][4] = {};
    #pragma unroll
    for (int jj = 0; jj < 4; ++jj) {
      #pragma unroll
      for (int ks = 0; ks < 2; ++ks) {
        bf16x8 kf = *(const bf16x8*)(kptr + (size_t)(kv0 + jj * 16 + l16) * 2048 + ks * 32 + quad * 8);
        #pragma unroll
        for (int i = 0; i < 2; ++i)
          s[i][jj] = __builtin_amdgcn_mfma_f32_16x16x32_bf16(qf[i][ks], kf, s[i][jj], 0, 0, 0);
      }
    }
    // hoist V-tile loads: issue now, consume after softmax (latency overlap)
    bf16x8 vf[8];
    #pragma unroll
    for (int ks = 0; ks < 2; ++ks)
      #pragma unroll
      for (int j = 0; j < 4; ++j)
        vf[ks * 4 + j] = *(const bf16x8*)(vptr + (size_t)(j * 16 + l16) * 2048 + kv0 + ks * 32 + quad * 8);
    // softmax: p = exp2(c2*s); accumulate l; store bf16 P to LDS
    #pragma unroll
    for (int i = 0; i < 2; ++i)
      #pragma unroll
      for (int jj = 0; jj < 4; ++jj)
        #pragma unroll
        for (int r = 0; r < 4; ++r) {
          const float p = exp2f(s[i][jj][r] * c2);
          lsum[i][r] += p;
          union { float f; unsigned u; } vv; vv.f = p;
          Pl[i * 16 + quad * 4 + r][jj * 16 + l16] = (u16)((vv.u + 0x8000u) >> 16);
        }
    // PV: o += P(32x64) . V^T(64x64)
    #pragma unroll
    for (int ks = 0; ks < 2; ++ks) {
      bf16x8 af0 = *(const bf16x8*)&Pl[l16][ks * 32 + quad * 8];
      bf16x8 af1 = *(const bf16x8*)&Pl[16 + l16][ks * 32 + quad * 8];
      #pragma unroll
      for (int j = 0; j < 4; ++j) {
        o[0][j] = __builtin_amdgcn_mfma_f32_16x16x32_bf16(af0, vf[ks * 4 + j], o[0][j], 0, 0, 0);
        o[1][j] = __builtin_amdgcn_mfma_f32_16x16x32_bf16(af1, vf[ks * 4 + j], o[1][j], 0, 0, 0);
      }
    }
  }

  // epilogue: reduce l over the 16 lanes of each quad, normalize, write ctx
  #pragma unroll
  for (int i = 0; i < 2; ++i)
    #pragma unroll
    for (int r = 0; r < 4; ++r) {
      float lv = lsum[i][r];
      #pragma unroll
      for (int d = 1; d < 16; d <<= 1) lv += __shfl_xor(lv, d, 64);
      lsum[i][r] = lv;
    }
  u16* cbase = ctx + (size_t)(b * 2048) * 1024 + h * 64;
  #pragma unroll
  for (int i = 0; i < 2; ++i)
    #pragma unroll
    for (int r = 0; r < 4; ++r) {
      const float inv = 1.0f / lsum[i][r];
      const int q = qbase + i * 16 + quad * 4 + r;
      #pragma unroll
      for (int j = 0; j < 4; ++j)
        cbase[(size_t)q * 1024 + j * 16 + l16] = f2bf(o[i][j][r] * inv);
    }
}

extern "C" void kernel_launch(void* const* d_in, const int* in_sizes, int n_in,
                              void* d_out, int out_size, void* d_ws, size_t ws_size,
                              hipStream_t stream) {
  (void)out_size;
  const float *x = nullptr, *wq = nullptr, *bq = nullptr, *wp = nullptr, *bp = nullptr;
  for (int i = 0; i < n_in; ++i) {
    switch (in_sizes[i]) {
      case 8388608: x  = (const float*)d_in[i]; break;
      case 3145728: wq = (const float*)d_in[i]; break;
      case 3072:    bq = (const float*)d_in[i]; break;
      case 1048576: wp = (const float*)d_in[i]; break;
      case 1024:    bp = (const float*)d_in[i]; break;
      default: break;
    }
  }
  if (!x || !wq || !bq || !wp || !bp) {
    x  = (const float*)d_in[0]; wq = (const float*)d_in[1];
    bq = (const float*)d_in[2]; wp = (const float*)d_in[3];
    bp = (const float*)d_in[4];
  }
  float* out = (float*)d_out;  // f32 output (established R7)

  const size_t NEED = 75497472;
  if (ws_size < NEED) return;

  char* ws = (char*)d_ws;
  u16* qkb = (u16*)(ws);              // [8192][2048] Q,K
  u16* vt  = (u16*)(ws + 33554432);   // [64][64][2048] V^T
  u16* xbf = (u16*)(ws + 50331648);   // x_bf, then ctx
  u16* wT1 = (u16*)(ws + 67108864);
  u16* wT2 = (u16*)(ws + 73400320);

  convert_x<<<8192, 256, 0, stream>>>(x, xbf);
  transpose_f32_bf16<<<dim3(96, 32), 256, 0, stream>>>(wq, wT1, 1024, 3072);
  transpose_f32_bf16<<<dim3(32, 32), 256, 0, stream>>>(wp, wT2, 1024, 1024);
  gemm1_qkv<<<dim3(24, 64), 256, 0, stream>>>(xbf, wT1, bq, qkb, vt, 1024);
  attn_fused<<<dim3(64, 64), 64, 0, stream>>>(qkb, vt, xbf /*ctx*/);
  gemm2_proj<<<dim3(8, 64), 256, 0, stream>>>(xbf /*ctx*/, wT2, bp, out, 1024);
}

// Round 11
// 326.134 us; speedup vs baseline: 1.6731x; 1.3759x over previous
//
#include <hip/hip_runtime.h>

typedef unsigned short u16;
typedef __attribute__((ext_vector_type(8))) short bf16x8;  // 8 bf16 (4 VGPRs)
typedef __attribute__((ext_vector_type(4))) float f32x4;   // MFMA C/D frag

__device__ __forceinline__ float bf2f(u16 x) {
  union { unsigned u; float f; } v; v.u = ((unsigned)x) << 16; return v.f;
}
__device__ __forceinline__ u16 f2bf(float f) {
  union { float f; unsigned u; } v; v.f = f;
  unsigned r = v.u + 0x7FFFu + ((v.u >> 16) & 1u);  // RNE
  return (u16)(r >> 16);
}
__device__ __forceinline__ float clampf(float v) {
  return fmaxf(fminf(v, 1.0e4f), -1.0e4f);
}

// ---------- convert x (f32) -> bf16 ----------
__global__ __launch_bounds__(256) void convert_x(
    const float* __restrict__ x, u16* __restrict__ xbf) {
  const int i0 = (blockIdx.x * 256 + threadIdx.x) * 4;
  const float4 v = *(const float4*)(x + i0);
  xbf[i0 + 0] = f2bf(v.x); xbf[i0 + 1] = f2bf(v.y);
  xbf[i0 + 2] = f2bf(v.z); xbf[i0 + 3] = f2bf(v.w);
}

// ---------- transpose f32 in[R][C] -> bf16 out[C][R] ----------
__global__ __launch_bounds__(256) void transpose_f32_bf16(
    const float* __restrict__ in, u16* __restrict__ out, int R, int C) {
  __shared__ u16 tile[32][33];
  const int bc = blockIdx.x * 32, br = blockIdx.y * 32;
  const int tx = threadIdx.x & 31, ty = threadIdx.x >> 5;
  #pragma unroll
  for (int i = ty; i < 32; i += 8)
    tile[i][tx] = f2bf(in[(size_t)(br + i) * C + bc + tx]);
  __syncthreads();
  #pragma unroll
  for (int i = ty; i < 32; i += 8)
    out[(size_t)(bc + i) * R + br + tx] = tile[tx][i];
}

// ---------- GEMM1: QKV projection, dual-output epilogue (unchanged) ----------
#define LDT 40  // 32 + 8 pad; 80B rows keep 16B alignment

__global__ __launch_bounds__(256) void gemm1_qkv(
    const u16* __restrict__ A, const u16* __restrict__ Bt,
    const float* __restrict__ bias, u16* __restrict__ qk,
    u16* __restrict__ vt, int K) {
  __shared__ u16 As[128 * LDT];
  __shared__ u16 Bs[128 * LDT];
  const int tid = threadIdx.x;
  const int m0 = blockIdx.y * 128, n0 = blockIdx.x * 128;
  const int wave = tid >> 6, lane = tid & 63;
  const int quad = lane >> 4, l16 = lane & 15;
  const int wm = (wave >> 1) * 64, wn = (wave & 1) * 64;
  const int sr = tid >> 2, sp = tid & 3;

  f32x4 acc[4][4] = {};
  const u16* gA = A + (size_t)(m0 + sr) * K + sp * 8;
  const u16* gB = Bt + (size_t)(n0 + sr) * K + sp * 8;

  for (int k0 = 0; k0 < K; k0 += 32) {
    *(bf16x8*)&As[sr * LDT + sp * 8]        = *(const bf16x8*)(gA + k0);
    *(bf16x8*)&As[(sr + 64) * LDT + sp * 8] = *(const bf16x8*)(gA + (size_t)64 * K + k0);
    *(bf16x8*)&Bs[sr * LDT + sp * 8]        = *(const bf16x8*)(gB + k0);
    *(bf16x8*)&Bs[(sr + 64) * LDT + sp * 8] = *(const bf16x8*)(gB + (size_t)64 * K + k0);
    __syncthreads();
    bf16x8 af[4], bfr[4];
    #pragma unroll
    for (int i = 0; i < 4; ++i)
      af[i] = *(const bf16x8*)&As[(wm + i * 16 + l16) * LDT + quad * 8];
    #pragma unroll
    for (int j = 0; j < 4; ++j)
      bfr[j] = *(const bf16x8*)&Bs[(wn + j * 16 + l16) * LDT + quad * 8];
    #pragma unroll
    for (int i = 0; i < 4; ++i)
      #pragma unroll
      for (int j = 0; j < 4; ++j)
        acc[i][j] = __builtin_amdgcn_mfma_f32_16x16x32_bf16(af[i], bfr[j], acc[i][j], 0, 0, 0);
    __syncthreads();
  }

  #pragma unroll
  for (int i = 0; i < 4; ++i) {
    const int row = m0 + wm + i * 16 + quad * 4;
    #pragma unroll
    for (int j = 0; j < 4; ++j) {
      const int col = n0 + wn + j * 16 + l16;
      const float bv = bias[col];
      if (col < 2048) {
        #pragma unroll
        for (int r = 0; r < 4; ++r)
          qk[(size_t)(row + r) * 2048 + col] = f2bf(clampf(acc[i][j][r] + bv));
      } else {
        const int d = col & 63;
        const int hh = (col - 2048) >> 6;
        #pragma unroll
        for (int r = 0; r < 4; ++r) {
          const int rr = row + r;
          const int bb = rr >> 11, ss = rr & 2047;
          vt[(size_t)(bb * 16 + hh) * 131072 + d * 2048 + ss] =
              f2bf(clampf(acc[i][j][r] + bv));
        }
      }
    }
  }
}

// ---------- GEMM2: out(f32) = ctx * w_proj^T + bias (unchanged) ----------
__global__ __launch_bounds__(256) void gemm2_proj(
    const u16* __restrict__ A, const u16* __restrict__ Bt,
    const float* __restrict__ bias, float* __restrict__ out, int K) {
  __shared__ u16 As[128 * LDT];
  __shared__ u16 Bs[128 * LDT];
  const int tid = threadIdx.x;
  const int m0 = blockIdx.y * 128, n0 = blockIdx.x * 128;
  const int wave = tid >> 6, lane = tid & 63;
  const int quad = lane >> 4, l16 = lane & 15;
  const int wm = (wave >> 1) * 64, wn = (wave & 1) * 64;
  const int sr = tid >> 2, sp = tid & 3;

  f32x4 acc[4][4] = {};
  const u16* gA = A + (size_t)(m0 + sr) * K + sp * 8;
  const u16* gB = Bt + (size_t)(n0 + sr) * K + sp * 8;

  for (int k0 = 0; k0 < K; k0 += 32) {
    *(bf16x8*)&As[sr * LDT + sp * 8]        = *(const bf16x8*)(gA + k0);
    *(bf16x8*)&As[(sr + 64) * LDT + sp * 8] = *(const bf16x8*)(gA + (size_t)64 * K + k0);
    *(bf16x8*)&Bs[sr * LDT + sp * 8]        = *(const bf16x8*)(gB + k0);
    *(bf16x8*)&Bs[(sr + 64) * LDT + sp * 8] = *(const bf16x8*)(gB + (size_t)64 * K + k0);
    __syncthreads();
    bf16x8 af[4], bfr[4];
    #pragma unroll
    for (int i = 0; i < 4; ++i)
      af[i] = *(const bf16x8*)&As[(wm + i * 16 + l16) * LDT + quad * 8];
    #pragma unroll
    for (int j = 0; j < 4; ++j)
      bfr[j] = *(const bf16x8*)&Bs[(wn + j * 16 + l16) * LDT + quad * 8];
    #pragma unroll
    for (int i = 0; i < 4; ++i)
      #pragma unroll
      for (int j = 0; j < 4; ++j)
        acc[i][j] = __builtin_amdgcn_mfma_f32_16x16x32_bf16(af[i], bfr[j], acc[i][j], 0, 0, 0);
    __syncthreads();
  }

  #pragma unroll
  for (int i = 0; i < 4; ++i) {
    const int row = m0 + wm + i * 16 + quad * 4;
    #pragma unroll
    for (int j = 0; j < 4; ++j) {
      const int col = n0 + wn + j * 16 + l16;
      const float bv = bias[col];
      #pragma unroll
      for (int r = 0; r < 4; ++r)
        out[(size_t)(row + r) * 1024 + col] = clampf(acc[i][j][r] + bv);
    }
  }
}

// ---------- fused flash attention, v5: LDS-shared K/V ----------
// R8/R10 pinned at ~8.2 TB/s of L2/L3 read traffic (2.11 GB/dispatch, two
// schedules, same time) => traffic-bound. v5: 4 waves/block share one staged
// K/V tile (128 q-rows per block) -> 4x traffic cut (528 MB). Pipelined:
// next tile's global loads issue before current tile's compute, so the
// vmcnt drain at the next barrier is covered. 4 blocks/CU (LDS 36.9 KB).
__global__ __launch_bounds__(256, 4) void attn_fused(
    const u16* __restrict__ qk, const u16* __restrict__ vt,
    u16* __restrict__ ctx) {
  __shared__ u16 Ks[64][72];       // K tile [kv][d], pad 72
  __shared__ u16 Vs[64][72];       // V^T tile [d][kv], pad 72
  __shared__ u16 Pl[4][32][72];    // per-wave P[32 q][64 kv]
  const int bh = blockIdx.x, qt = blockIdx.y;
  const int b = bh >> 4, h = bh & 15;
  const int tid = threadIdx.x;
  const int w = tid >> 6, lane = tid & 63;
  const int quad = lane >> 4, l16 = lane & 15;
  const int qbase = qt * 128 + w * 32;

  const u16* qptr = qk + (size_t)(b * 2048) * 2048 + h * 64;
  bf16x8 qf[2][2];
  #pragma unroll
  for (int i = 0; i < 2; ++i)
    #pragma unroll
    for (int ks = 0; ks < 2; ++ks)
      qf[i][ks] = *(const bf16x8*)(qptr + (size_t)(qbase + i * 16 + l16) * 2048 + ks * 32 + quad * 8);

  const u16* kptr = qk + (size_t)(b * 2048) * 2048 + 1024 + h * 64;
  const u16* vptr = vt + (size_t)bh * 131072;

  // staging role: thread t covers rows srow, srow+32; 8 threads x 8 elems/row
  const int srow = tid >> 3, scol = (tid & 7) * 8;

  f32x4 o[2][4] = {};
  f32x4 lsum[2] = {};
  const float c2 = 0.125f * 1.44269504088896340736f;  // SCALE * log2(e)

  // prologue: fetch tile 0 into registers
  bf16x8 k0 = *(const bf16x8*)(kptr + (size_t)srow * 2048 + scol);
  bf16x8 k1 = *(const bf16x8*)(kptr + (size_t)(srow + 32) * 2048 + scol);
  bf16x8 v0 = *(const bf16x8*)(vptr + (size_t)srow * 2048 + scol);
  bf16x8 v1 = *(const bf16x8*)(vptr + (size_t)(srow + 32) * 2048 + scol);

  for (int kv0 = 0; kv0 < 2048; kv0 += 64) {
    __syncthreads();  // all waves done reading previous tile
    *(bf16x8*)&Ks[srow][scol]      = k0;
    *(bf16x8*)&Ks[srow + 32][scol] = k1;
    *(bf16x8*)&Vs[srow][scol]      = v0;
    *(bf16x8*)&Vs[srow + 32][scol] = v1;
    __syncthreads();
    // issue next tile's loads now; latency covered by compute below
    const int kvn = (kv0 + 64) & 2047;  // last iter wraps (valid, discarded)
    k0 = *(const bf16x8*)(kptr + (size_t)(kvn + srow) * 2048 + scol);
    k1 = *(const bf16x8*)(kptr + (size_t)(kvn + srow + 32) * 2048 + scol);
    v0 = *(const bf16x8*)(vptr + (size_t)srow * 2048 + kvn + scol);
    v1 = *(const bf16x8*)(vptr + (size_t)(srow + 32) * 2048 + kvn + scol);

    // QK^T from LDS K tile
    f32x4 s[2][4] = {};
    #pragma unroll
    for (int jj = 0; jj < 4; ++jj) {
      #pragma unroll
      for (int ks = 0; ks < 2; ++ks) {
        bf16x8 kf = *(const bf16x8*)&Ks[jj * 16 + l16][ks * 32 + quad * 8];
        #pragma unroll
        for (int i = 0; i < 2; ++i)
          s[i][jj] = __builtin_amdgcn_mfma_f32_16x16x32_bf16(qf[i][ks], kf, s[i][jj], 0, 0, 0);
      }
    }
    // softmax: p = exp2(c2*s); accumulate l; bf16 P -> wave-private LDS
    #pragma unroll
    for (int i = 0; i < 2; ++i)
      #pragma unroll
      for (int jj = 0; jj < 4; ++jj)
        #pragma unroll
        for (int r = 0; r < 4; ++r) {
          const float p = exp2f(s[i][jj][r] * c2);
          lsum[i][r] += p;
          union { float f; unsigned u; } vv; vv.f = p;
          Pl[w][i * 16 + quad * 4 + r][jj * 16 + l16] = (u16)((vv.u + 0x8000u) >> 16);
        }
    // PV from LDS V tile
    #pragma unroll
    for (int ks = 0; ks < 2; ++ks) {
      bf16x8 af0 = *(const bf16x8*)&Pl[w][l16][ks * 32 + quad * 8];
      bf16x8 af1 = *(const bf16x8*)&Pl[w][16 + l16][ks * 32 + quad * 8];
      #pragma unroll
      for (int j = 0; j < 4; ++j) {
        bf16x8 vf = *(const bf16x8*)&Vs[j * 16 + l16][ks * 32 + quad * 8];
        o[0][j] = __builtin_amdgcn_mfma_f32_16x16x32_bf16(af0, vf, o[0][j], 0, 0, 0);
        o[1][j] = __builtin_amdgcn_mfma_f32_16x16x32_bf16(af1, vf, o[1][j], 0, 0, 0);
      }
    }
  }

  // epilogue: reduce l over the 16 lanes of each quad, normalize, write ctx
  #pragma unroll
  for (int i = 0; i < 2; ++i)
    #pragma unroll
    for (int r = 0; r < 4; ++r) {
      float lv = lsum[i][r];
      #pragma unroll
      for (int d = 1; d < 16; d <<= 1) lv += __shfl_xor(lv, d, 64);
      lsum[i][r] = lv;
    }
  u16* cbase = ctx + (size_t)(b * 2048) * 1024 + h * 64;
  #pragma unroll
  for (int i = 0; i < 2; ++i)
    #pragma unroll
    for (int r = 0; r < 4; ++r) {
      const float inv = 1.0f / lsum[i][r];
      const int q = qbase + i * 16 + quad * 4 + r;
      #pragma unroll
      for (int j = 0; j < 4; ++j)
        cbase[(size_t)q * 1024 + j * 16 + l16] = f2bf(o[i][j][r] * inv);
    }
}

extern "C" void kernel_launch(void* const* d_in, const int* in_sizes, int n_in,
                              void* d_out, int out_size, void* d_ws, size_t ws_size,
                              hipStream_t stream) {
  (void)out_size;
  const float *x = nullptr, *wq = nullptr, *bq = nullptr, *wp = nullptr, *bp = nullptr;
  for (int i = 0; i < n_in; ++i) {
    switch (in_sizes[i]) {
      case 8388608: x  = (const float*)d_in[i]; break;
      case 3145728: wq = (const float*)d_in[i]; break;
      case 3072:    bq = (const float*)d_in[i]; break;
      case 1048576: wp = (const float*)d_in[i]; break;
      case 1024:    bp = (const float*)d_in[i]; break;
      default: break;
    }
  }
  if (!x || !wq || !bq || !wp || !bp) {
    x  = (const float*)d_in[0]; wq = (const float*)d_in[1];
    bq = (const float*)d_in[2]; wp = (const float*)d_in[3];
    bp = (const float*)d_in[4];
  }
  float* out = (float*)d_out;  // f32 output (established R7)

  const size_t NEED = 75497472;
  if (ws_size < NEED) return;

  char* ws = (char*)d_ws;
  u16* qkb = (u16*)(ws);              // [8192][2048] Q,K
  u16* vt  = (u16*)(ws + 33554432);   // [64][64][2048] V^T
  u16* xbf = (u16*)(ws + 50331648);   // x_bf, then ctx
  u16* wT1 = (u16*)(ws + 67108864);
  u16* wT2 = (u16*)(ws + 73400320);

  convert_x<<<8192, 256, 0, stream>>>(x, xbf);
  transpose_f32_bf16<<<dim3(96, 32), 256, 0, stream>>>(wq, wT1, 1024, 3072);
  transpose_f32_bf16<<<dim3(32, 32), 256, 0, stream>>>(wp, wT2, 1024, 1024);
  gemm1_qkv<<<dim3(24, 64), 256, 0, stream>>>(xbf, wT1, bq, qkb, vt, 1024);
  attn_fused<<<dim3(64, 16), 256, 0, stream>>>(qkb, vt, xbf /*ctx*/);
  gemm2_proj<<<dim3(8, 64), 256, 0, stream>>>(xbf /*ctx*/, wT2, bp, out, 1024);
}